// Round 4
// baseline (443.545 us; speedup 1.0000x reference)
//
#include <hip/hip_runtime.h>
#include <hip/hip_bf16.h>
#include <stdint.h>

#define NTOK 392
#define DIM  128
#define NH   4
#define HD   32
#define NCH  13
#define KVST 36    // chunk-LDS row stride (shorts): 18 dwords -> worst 2-way (free)
#define L2E  1.44269504f

typedef __attribute__((ext_vector_type(4))) float f32x4;
typedef __attribute__((ext_vector_type(4))) short s16x4;
typedef __attribute__((ext_vector_type(8))) short s16x8;

union Frag { s16x8 v; struct { s16x4 lo, hi; } h; };
union PF { s16x8 v; uint32_t u[4]; };

__device__ __forceinline__ short f2bf(float f) {
  union { float f; uint32_t u; } v; v.f = f;
  uint32_t r = v.u + 0x7fffu + ((v.u >> 16) & 1u);
  return (short)(r >> 16);
}
__device__ __forceinline__ s16x4 cvt4(f32x4 a) {
  s16x4 r; r.x = f2bf(a.x); r.y = f2bf(a.y); r.z = f2bf(a.z); r.w = f2bf(a.w);
  return r;
}

// ---------------- K0: expand relative-position bias to [h][n][m] f32 ----------
__global__ void k_bias(const float* __restrict__ bt, const int* __restrict__ ri,
                       float* __restrict__ bias_pre) {
  int i = blockIdx.x * 256 + threadIdx.x;
  if (i >= NTOK * NTOK) return;
  int idx = ri[i];
  f32x4 t = *(const f32x4*)(bt + 4 * idx);
  bias_pre[i]                   = t.x;
  bias_pre[NTOK*NTOK + i]       = t.y;
  bias_pre[2*NTOK*NTOK + i]     = t.z;
  bias_pre[3*NTOK*NTOK + i]     = t.w;
}

// ------- K1: qkv = x @ qkv_w^T, bf16 out, q pre-scaled; fused z-loop ---------
__global__ __launch_bounds__(256, 2)
void k_qkv(const float* __restrict__ x, const float* __restrict__ qkv_w,
           short* __restrict__ q_ws, short* __restrict__ k_ws,
           short* __restrict__ v_ws) {
  __shared__ short xs[64 * 136];
  __shared__ short wl[128 * 136];
  const int t  = threadIdx.x;
  const int m0 = blockIdx.x * 64;
  {
    const int r = t >> 2, c0 = (t & 3) * 32;
    const float* src = x + (size_t)(m0 + r) * DIM + c0;
    short* dst = xs + r * 136 + c0;
    #pragma unroll
    for (int i = 0; i < 8; ++i)
      *(s16x4*)(dst + 4*i) = cvt4(*(const f32x4*)(src + 4*i));
  }
  const int l = t & 63, w = t >> 6, lr = l & 15, g = l >> 4;
  const int m = m0 + w * 16 + lr;
  const int b = m / NTOK;
  const int n = m - b * NTOK;
  #pragma unroll 1
  for (int z = 0; z < 3; ++z) {
    {
      const int r = t >> 1, c0 = (t & 1) * 64;
      const float* src = qkv_w + (size_t)(z * DIM + r) * DIM + c0;
      short* dst = wl + r * 136 + c0;
      #pragma unroll
      for (int i = 0; i < 16; ++i)
        *(s16x4*)(dst + 4*i) = cvt4(*(const f32x4*)(src + 4*i));
    }
    __syncthreads();
    f32x4 acc[8] = {};
    #pragma unroll
    for (int ks = 0; ks < 4; ++ks) {
      const int k0 = ks * 32 + 4 * g;
      Frag xb;
      const short* bp = xs + (w * 16 + lr) * 136 + k0;
      xb.h.lo = *(const s16x4*)bp; xb.h.hi = *(const s16x4*)(bp + 16);
      #pragma unroll
      for (int ct = 0; ct < 8; ++ct) {
        const short* ap = wl + (ct * 16 + lr) * 136 + k0;
        Frag wa; wa.h.lo = *(const s16x4*)ap; wa.h.hi = *(const s16x4*)(ap + 16);
        acc[ct] = __builtin_amdgcn_mfma_f32_16x16x32_bf16(wa.v, xb.v, acc[ct], 0, 0, 0);
      }
    }
    short* outp = (z == 0) ? q_ws : (z == 1 ? k_ws : v_ws);
    const float scale = (z == 0) ? 0.17677669529663689f : 1.0f;
    #pragma unroll
    for (int ct = 0; ct < 8; ++ct) {
      const int c0 = ct * 16 + 4 * g;       // 4 consecutive channels
      const int hh = c0 >> 5, d = c0 & 31;
      f32x4 sc = acc[ct];
      sc.x *= scale; sc.y *= scale; sc.z *= scale; sc.w *= scale;
      *(s16x4*)(outp + (((size_t)b * NH + hh) * NTOK + n) * HD + d) = cvt4(sc);
    }
    __syncthreads();
  }
}

// ---- K2: per-window attention, 4 heads/block, streamed K/V chunks -----------
// One block per window: mask rows read ONCE per dispatch (170MB logical vs
// 680MB before). K/V double-buffered per 32-kv chunk; 4 lockstep rounds of
// 8 waves x 16 q-rows. Softmax body identical to verified r3 kernel.
__global__ __launch_bounds__(512, 2)
void k_attn(const short* __restrict__ q_ws, const short* __restrict__ k_ws,
            const short* __restrict__ v_ws, const float* __restrict__ mask,
            const float* __restrict__ bias_pre, short* __restrict__ y_ws) {
  __shared__ short Kl[2][NH][32][KVST];   // [buf][h][kv][d]
  __shared__ short Vt[2][NH][32][KVST];   // [buf][h][d][kv]
  const int t = threadIdx.x;
  const int b = blockIdx.x;
  const int l = t & 63, w = t >> 6, lr = l & 15, g = l >> 4;
  const int og0 = 4 * g, og1 = 16 + 4 * g;
  // staging ids: thread -> (head, kv-row, 16B quarter)
  const int srow = t >> 2, sq4 = t & 3;
  const int sh = srow >> 5, skv = srow & 31;
  const short* kgp = k_ws + ((size_t)(b * NH + sh) * NTOK) * HD + sq4 * 8;
  const short* vgp = v_ws + ((size_t)(b * NH + sh) * NTOK) * HD + sq4 * 8;
  const float* mp = mask + (size_t)b * NTOK * NTOK;
  const s16x8 kz = {0, 0, 0, 0, 0, 0, 0, 0};

  #pragma unroll 1
  for (int r = 0; r < 4; ++r) {
    const int T = r * 8 + w;
    const bool valid = (T < 25);
    const int qrow = T * 16 + lr;
    const int qc = qrow < NTOK ? qrow : NTOK - 1;
    Frag qf[NH];
    const float* mrow = mp + (size_t)qc * NTOK;
    const float* brow0 = bias_pre + (size_t)qc * NTOK;
    f32x4 o[NH][2];
    float mrun[NH], nmrl[NH], lrun[NH];
    f32x4 mbc[NH][2], mbn[NH][2];
    if (valid) {
      #pragma unroll
      for (int hh = 0; hh < NH; ++hh) {
        const short* qa = q_ws + ((size_t)(b * NH + hh) * NTOK + qc) * HD + 4 * g;
        qf[hh].h.lo = *(const s16x4*)qa; qf[hh].h.hi = *(const s16x4*)(qa + 16);
        o[hh][0] = (f32x4){0,0,0,0}; o[hh][1] = (f32x4){0,0,0,0};
        mrun[hh] = 0.f; nmrl[hh] = 0.f; lrun[hh] = 0.f;
      }
      f32x4 m0 = *(const f32x4*)(mrow + og0), m1 = *(const f32x4*)(mrow + og1);
      #pragma unroll
      for (int hh = 0; hh < NH; ++hh) {
        const float* br = brow0 + (size_t)hh * NTOK * NTOK;
        mbc[hh][0] = m0 + *(const f32x4*)(br + og0);
        mbc[hh][1] = m1 + *(const f32x4*)(br + og1);
      }
    }
    // stage chunk 0 into buf0 (prev round's last compute read buf0; its
    // trailing __syncthreads already passed)
    {
      Frag kr, vr; kr.v = kz; vr.v = kz;
      if (skv < NTOK) {   // chunk 0: kv = skv
        kr.v = *(const s16x8*)(kgp + skv * HD);
        vr.v = *(const s16x8*)(vgp + skv * HD);
      }
      short* kd = &Kl[0][sh][skv][sq4 * 8];
      *(s16x4*)kd = kr.h.lo; *(s16x4*)(kd + 4) = kr.h.hi;
      #pragma unroll
      for (int i = 0; i < 8; ++i) Vt[0][sh][sq4 * 8 + i][skv] = vr.v[i];
    }
    __syncthreads();
    #pragma unroll 1
    for (int c = 0; c < NCH; ++c) {
      const int cb = c & 1, nbuf = cb ^ 1;
      Frag kr, vr;
      if (c < NCH - 1) {
        kr.v = kz; vr.v = kz;
        const int kv = (c + 1) * 32 + skv;
        if (kv < NTOK) {
          kr.v = *(const s16x8*)(kgp + kv * HD);
          vr.v = *(const s16x8*)(vgp + kv * HD);
        }
        if (valid) {
          if (c + 1 <= 11) {
            const int c0 = (c + 1) * 32 + og0, c1 = (c + 1) * 32 + og1;
            f32x4 m0 = *(const f32x4*)(mrow + c0), m1 = *(const f32x4*)(mrow + c1);
            #pragma unroll
            for (int hh = 0; hh < NH; ++hh) {
              const float* br = brow0 + (size_t)hh * NTOK * NTOK;
              mbn[hh][0] = m0 + *(const f32x4*)(br + c0);
              mbn[hh][1] = m1 + *(const f32x4*)(br + c1);
            }
          } else {   // tail chunk 12: kv 384..391 real, rest poisoned
            const f32x4 neg = {-3e30f, -3e30f, -3e30f, -3e30f};
            int c0 = 384 + og0; if (c0 > NTOK - 4) c0 = NTOK - 4;
            f32x4 m0 = *(const f32x4*)(mrow + c0);
            #pragma unroll
            for (int hh = 0; hh < NH; ++hh) {
              const float* br = brow0 + (size_t)hh * NTOK * NTOK;
              f32x4 tv = m0 + *(const f32x4*)(br + c0);
              mbn[hh][0] = (g < 2) ? tv : neg;
              mbn[hh][1] = neg;
            }
          }
        }
      }
      if (valid) {
        #pragma unroll
        for (int hh = 0; hh < NH; ++hh) {
          Frag ka0, ka1;
          { const short* p0 = &Kl[cb][hh][lr][4 * g];
            ka0.h.lo = *(const s16x4*)p0; ka0.h.hi = *(const s16x4*)(p0 + 16);
            const short* p1 = &Kl[cb][hh][16 + lr][4 * g];
            ka1.h.lo = *(const s16x4*)p1; ka1.h.hi = *(const s16x4*)(p1 + 16); }
          f32x4 z4 = {0,0,0,0};
          f32x4 s0 = __builtin_amdgcn_mfma_f32_16x16x32_bf16(ka0.v, qf[hh].v, z4, 0,0,0);
          f32x4 s1 = __builtin_amdgcn_mfma_f32_16x16x32_bf16(ka1.v, qf[hh].v, z4, 0,0,0);
          s0 += mbc[hh][0]; s1 += mbc[hh][1];
          float cm = fmaxf(fmaxf(fmaxf(s0.x, s0.y), fmaxf(s0.z, s0.w)),
                           fmaxf(fmaxf(s1.x, s1.y), fmaxf(s1.z, s1.w)));
          if (__any(cm > mrun[hh] + 8.f)) {
            float tmx = fmaxf(cm, __shfl_xor(cm, 16));
            tmx = fmaxf(tmx, __shfl_xor(tmx, 32));
            const float mnew = fmaxf(mrun[hh], tmx);
            const float al = exp2f((mrun[hh] - mnew) * L2E);
            #pragma unroll
            for (int rr = 0; rr < 4; ++rr) { o[hh][0][rr] *= al; o[hh][1][rr] *= al; }
            lrun[hh] *= al; mrun[hh] = mnew; nmrl[hh] = -mnew * L2E;
          }
          float p0 = exp2f(fmaf(s0.x, L2E, nmrl[hh]));
          float p1 = exp2f(fmaf(s0.y, L2E, nmrl[hh]));
          float p2 = exp2f(fmaf(s0.z, L2E, nmrl[hh]));
          float p3 = exp2f(fmaf(s0.w, L2E, nmrl[hh]));
          float p4 = exp2f(fmaf(s1.x, L2E, nmrl[hh]));
          float p5 = exp2f(fmaf(s1.y, L2E, nmrl[hh]));
          float p6 = exp2f(fmaf(s1.z, L2E, nmrl[hh]));
          float p7 = exp2f(fmaf(s1.w, L2E, nmrl[hh]));
          lrun[hh] += ((p0 + p1) + (p2 + p3)) + ((p4 + p5) + (p6 + p7));
          PF pf;
          asm("v_cvt_pk_bf16_f32 %0, %1, %2" : "=v"(pf.u[0]) : "v"(p0), "v"(p1));
          asm("v_cvt_pk_bf16_f32 %0, %1, %2" : "=v"(pf.u[1]) : "v"(p2), "v"(p3));
          asm("v_cvt_pk_bf16_f32 %0, %1, %2" : "=v"(pf.u[2]) : "v"(p4), "v"(p5));
          asm("v_cvt_pk_bf16_f32 %0, %1, %2" : "=v"(pf.u[3]) : "v"(p6), "v"(p7));
          Frag vf0, vf1;
          { const short* v0 = &Vt[cb][hh][lr][4 * g];
            vf0.h.lo = *(const s16x4*)v0; vf0.h.hi = *(const s16x4*)(v0 + 16);
            const short* v1 = &Vt[cb][hh][16 + lr][4 * g];
            vf1.h.lo = *(const s16x4*)v1; vf1.h.hi = *(const s16x4*)(v1 + 16); }
          o[hh][0] = __builtin_amdgcn_mfma_f32_16x16x32_bf16(vf0.v, pf.v, o[hh][0], 0,0,0);
          o[hh][1] = __builtin_amdgcn_mfma_f32_16x16x32_bf16(vf1.v, pf.v, o[hh][1], 0,0,0);
        }
        if (c < NCH - 1) {
          #pragma unroll
          for (int hh = 0; hh < NH; ++hh) { mbc[hh][0] = mbn[hh][0]; mbc[hh][1] = mbn[hh][1]; }
        }
      }
      if (c < NCH - 1) {   // write next chunk after compute (loads hidden)
        short* kd = &Kl[nbuf][sh][skv][sq4 * 8];
        *(s16x4*)kd = kr.h.lo; *(s16x4*)(kd + 4) = kr.h.hi;
        #pragma unroll
        for (int i = 0; i < 8; ++i) Vt[nbuf][sh][sq4 * 8 + i][skv] = vr.v[i];
      }
      __syncthreads();
    }
    if (valid && qrow < NTOK) {
      #pragma unroll
      for (int hh = 0; hh < NH; ++hh) {
        float lt = lrun[hh] + __shfl_xor(lrun[hh], 16);
        lt += __shfl_xor(lt, 32);
        const float inv = 1.0f / lt;
        short* yb = y_ws + ((size_t)b * NTOK + qrow) * DIM + hh * HD;
        s16x4 r0, r1;
        #pragma unroll
        for (int rr = 0; rr < 4; ++rr) {
          r0[rr] = f2bf(o[hh][0][rr] * inv);
          r1[rr] = f2bf(o[hh][1][rr] * inv);
        }
        *(s16x4*)(yb + 4 * g) = r0;
        *(s16x4*)(yb + 16 + 4 * g) = r1;
      }
    }
  }
}

// ---------------- K3: out = y @ proj_w^T + proj_b -----------------------------
__global__ __launch_bounds__(256, 2)
void k_proj(const short* __restrict__ y_ws, const float* __restrict__ pw,
            const float* __restrict__ pb, float* __restrict__ out) {
  __shared__ short ys[64 * 136];
  __shared__ short wl[128 * 136];
  const int t = threadIdx.x;
  const int m0 = blockIdx.x * 64;
  {
    const int r = t >> 2, c0 = (t & 3) * 32;
    const s16x4* src = (const s16x4*)(y_ws + (size_t)(m0 + r) * DIM + c0);
    short* dst = ys + r * 136 + c0;
    #pragma unroll
    for (int i = 0; i < 8; ++i) *(s16x4*)(dst + 4*i) = src[i];
  }
  {
    const int r = t >> 1, c0 = (t & 1) * 64;
    const float* src = pw + (size_t)r * DIM + c0;
    short* dst = wl + r * 136 + c0;
    #pragma unroll
    for (int i = 0; i < 16; ++i)
      *(s16x4*)(dst + 4*i) = cvt4(*(const f32x4*)(src + 4*i));
  }
  __syncthreads();
  const int l = t & 63, w = t >> 6, lr = l & 15, g = l >> 4;
  const int m = m0 + w * 16 + lr;
  f32x4 acc[8] = {};
  #pragma unroll
  for (int ks = 0; ks < 4; ++ks) {
    const int k0 = ks * 32 + 4 * g;
    Frag ya;
    const short* bp = ys + (w * 16 + lr) * 136 + k0;
    ya.h.lo = *(const s16x4*)bp; ya.h.hi = *(const s16x4*)(bp + 16);
    #pragma unroll
    for (int ct = 0; ct < 8; ++ct) {
      const short* ap = wl + (ct * 16 + lr) * 136 + k0;
      Frag wa; wa.h.lo = *(const s16x4*)ap; wa.h.hi = *(const s16x4*)(ap + 16);
      acc[ct] = __builtin_amdgcn_mfma_f32_16x16x32_bf16(wa.v, ya.v, acc[ct], 0, 0, 0);
    }
  }
  #pragma unroll
  for (int ct = 0; ct < 8; ++ct) {
    const int c0 = ct * 16 + 4 * g;
    const f32x4 pbv = *(const f32x4*)(pb + c0);
    f32x4 res = acc[ct] + pbv;
    *(f32x4*)(out + (size_t)m * DIM + c0) = res;
  }
}

extern "C" void kernel_launch(void* const* d_in, const int* in_sizes, int n_in,
                              void* d_out, int out_size, void* d_ws, size_t ws_size,
                              hipStream_t stream) {
  const float* x    = (const float*)d_in[0];
  const float* mask = (const float*)d_in[1];
  const float* bt   = (const float*)d_in[2];
  const int*   ri   = (const int*)d_in[3];
  const float* qkvw = (const float*)d_in[4];
  const float* pw   = (const float*)d_in[5];
  const float* pb   = (const float*)d_in[6];
  float* out = (float*)d_out;
  // ws layout: 4 x 25.69MB bf16 tensors + 2.46MB f32 bias = ~105.2MB
  const size_t TEN = (size_t)256 * NH * NTOK * HD;   // 12,845,056
  short* q_ws = (short*)d_ws;
  short* k_ws = q_ws + TEN;
  short* v_ws = k_ws + TEN;
  short* y_ws = v_ws + TEN;
  float* bias_pre = (float*)(y_ws + TEN);
  k_bias<<<(NTOK * NTOK + 255) / 256, 256, 0, stream>>>(bt, ri, bias_pre);
  k_qkv<<<1568, 256, 0, stream>>>(x, qkvw, q_ws, k_ws, v_ws);
  k_attn<<<256, 512, 0, stream>>>(q_ws, k_ws, v_ws, mask, bias_pre, y_ws);
  k_proj<<<1568, 256, 0, stream>>>(y_ws, pw, pb, out);
}

// Round 5
// 263.776 us; speedup vs baseline: 1.6815x; 1.6815x over previous
//
#include <hip/hip_runtime.h>
#include <hip/hip_bf16.h>
#include <stdint.h>

#define NTOK 392
#define DIM  128
#define NH   4
#define HD   32
#define NKVP 416   // 13*32 padded keys
#define NCH  13
#define KST  36    // K_lds stride (shorts): 18*r mod 32 distinct -> conflict-free
#define VST  420   // Vt_lds stride (shorts): 210 dwords; 18d mod 32 distinct
#define L2E  1.44269504f

typedef __attribute__((ext_vector_type(4))) float f32x4;
typedef __attribute__((ext_vector_type(4))) short s16x4;
typedef __attribute__((ext_vector_type(8))) short s16x8;

union Frag { s16x8 v; struct { s16x4 lo, hi; } h; };
union PF { s16x8 v; uint32_t u[4]; };

__device__ __forceinline__ short f2bf(float f) {
  union { float f; uint32_t u; } v; v.f = f;
  uint32_t r = v.u + 0x7fffu + ((v.u >> 16) & 1u);
  return (short)(r >> 16);
}
__device__ __forceinline__ s16x4 cvt4(f32x4 a) {
  s16x4 r; r.x = f2bf(a.x); r.y = f2bf(a.y); r.z = f2bf(a.z); r.w = f2bf(a.w);
  return r;
}

// mask+bias chunk fetch, with tail-chunk pad poison (c2 == 12)
__device__ __forceinline__ void load_mb(const float* mrow, const float* brow,
                                        int c2, int og0, int og1, int g,
                                        f32x4& b0, f32x4& b1) {
  if (c2 <= 11) {
    const int a0 = c2 * 32 + og0, a1 = c2 * 32 + og1;
    b0 = *(const f32x4*)(mrow + a0) + *(const f32x4*)(brow + a0);
    b1 = *(const f32x4*)(mrow + a1) + *(const f32x4*)(brow + a1);
  } else {   // kv 384..391 real, 392..415 pad
    const f32x4 neg = {-3e30f, -3e30f, -3e30f, -3e30f};
    int a0 = 384 + og0; if (a0 > NTOK - 4) a0 = NTOK - 4;
    f32x4 tv = *(const f32x4*)(mrow + a0) + *(const f32x4*)(brow + a0);
    b0 = (g < 2) ? tv : neg;
    b1 = neg;
  }
}

// online-softmax + PV step for one stream (verified r3 body)
__device__ __forceinline__ void sm_pv(f32x4 s0, f32x4 s1,
                                      f32x4& o0, f32x4& o1,
                                      float& mrun, float& nmrl, float& lrun,
                                      const Frag& vf0, const Frag& vf1) {
  float cm = fmaxf(fmaxf(fmaxf(s0.x, s0.y), fmaxf(s0.z, s0.w)),
                   fmaxf(fmaxf(s1.x, s1.y), fmaxf(s1.z, s1.w)));
  if (__any(cm > mrun + 8.f)) {         // rare: true running-max rescale
    float tmx = fmaxf(cm, __shfl_xor(cm, 16));
    tmx = fmaxf(tmx, __shfl_xor(tmx, 32));
    const float mnew = fmaxf(mrun, tmx);
    const float al = exp2f((mrun - mnew) * L2E);
    #pragma unroll
    for (int rr = 0; rr < 4; ++rr) { o0[rr] *= al; o1[rr] *= al; }
    lrun *= al; mrun = mnew; nmrl = -mnew * L2E;
  }
  float p0 = exp2f(fmaf(s0.x, L2E, nmrl));
  float p1 = exp2f(fmaf(s0.y, L2E, nmrl));
  float p2 = exp2f(fmaf(s0.z, L2E, nmrl));
  float p3 = exp2f(fmaf(s0.w, L2E, nmrl));
  float p4 = exp2f(fmaf(s1.x, L2E, nmrl));
  float p5 = exp2f(fmaf(s1.y, L2E, nmrl));
  float p6 = exp2f(fmaf(s1.z, L2E, nmrl));
  float p7 = exp2f(fmaf(s1.w, L2E, nmrl));
  lrun += ((p0 + p1) + (p2 + p3)) + ((p4 + p5) + (p6 + p7));
  PF pf;
  asm("v_cvt_pk_bf16_f32 %0, %1, %2" : "=v"(pf.u[0]) : "v"(p0), "v"(p1));
  asm("v_cvt_pk_bf16_f32 %0, %1, %2" : "=v"(pf.u[1]) : "v"(p2), "v"(p3));
  asm("v_cvt_pk_bf16_f32 %0, %1, %2" : "=v"(pf.u[2]) : "v"(p4), "v"(p5));
  asm("v_cvt_pk_bf16_f32 %0, %1, %2" : "=v"(pf.u[3]) : "v"(p6), "v"(p7));
  o0 = __builtin_amdgcn_mfma_f32_16x16x32_bf16(vf0.v, pf.v, o0, 0, 0, 0);
  o1 = __builtin_amdgcn_mfma_f32_16x16x32_bf16(vf1.v, pf.v, o1, 0, 0, 0);
}

// ---------------- K0: expand relative-position bias to [h][n][m] f32 ----------
__global__ void k_bias(const float* __restrict__ bt, const int* __restrict__ ri,
                       float* __restrict__ bias_pre) {
  int i = blockIdx.x * 256 + threadIdx.x;
  if (i >= NTOK * NTOK) return;
  int idx = ri[i];
  f32x4 t = *(const f32x4*)(bt + 4 * idx);
  bias_pre[i]                   = t.x;
  bias_pre[NTOK*NTOK + i]       = t.y;
  bias_pre[2*NTOK*NTOK + i]     = t.z;
  bias_pre[3*NTOK*NTOK + i]     = t.w;
}

// ------- K1: qkv = x @ qkv_w^T, bf16 out, q pre-scaled; fused z-loop ---------
__global__ __launch_bounds__(256, 2)
void k_qkv(const float* __restrict__ x, const float* __restrict__ qkv_w,
           short* __restrict__ q_ws, short* __restrict__ k_ws,
           short* __restrict__ v_ws) {
  __shared__ short xs[64 * 136];
  __shared__ short wl[128 * 136];
  const int t  = threadIdx.x;
  const int m0 = blockIdx.x * 64;
  {
    const int r = t >> 2, c0 = (t & 3) * 32;
    const float* src = x + (size_t)(m0 + r) * DIM + c0;
    short* dst = xs + r * 136 + c0;
    #pragma unroll
    for (int i = 0; i < 8; ++i)
      *(s16x4*)(dst + 4*i) = cvt4(*(const f32x4*)(src + 4*i));
  }
  const int l = t & 63, w = t >> 6, lr = l & 15, g = l >> 4;
  const int m = m0 + w * 16 + lr;
  const int b = m / NTOK;
  const int n = m - b * NTOK;
  #pragma unroll 1
  for (int z = 0; z < 3; ++z) {
    {
      const int r = t >> 1, c0 = (t & 1) * 64;
      const float* src = qkv_w + (size_t)(z * DIM + r) * DIM + c0;
      short* dst = wl + r * 136 + c0;
      #pragma unroll
      for (int i = 0; i < 16; ++i)
        *(s16x4*)(dst + 4*i) = cvt4(*(const f32x4*)(src + 4*i));
    }
    __syncthreads();
    f32x4 acc[8] = {};
    #pragma unroll
    for (int ks = 0; ks < 4; ++ks) {
      const int k0 = ks * 32 + 4 * g;
      Frag xb;
      const short* bp = xs + (w * 16 + lr) * 136 + k0;
      xb.h.lo = *(const s16x4*)bp; xb.h.hi = *(const s16x4*)(bp + 16);
      #pragma unroll
      for (int ct = 0; ct < 8; ++ct) {
        const short* ap = wl + (ct * 16 + lr) * 136 + k0;
        Frag wa; wa.h.lo = *(const s16x4*)ap; wa.h.hi = *(const s16x4*)(ap + 16);
        acc[ct] = __builtin_amdgcn_mfma_f32_16x16x32_bf16(wa.v, xb.v, acc[ct], 0, 0, 0);
      }
    }
    short* outp = (z == 0) ? q_ws : (z == 1 ? k_ws : v_ws);
    const float scale = (z == 0) ? 0.17677669529663689f : 1.0f;
    #pragma unroll
    for (int ct = 0; ct < 8; ++ct) {
      const int c0 = ct * 16 + 4 * g;       // 4 consecutive channels
      const int hh = c0 >> 5, d = c0 & 31;
      f32x4 sc = acc[ct];
      sc.x *= scale; sc.y *= scale; sc.z *= scale; sc.w *= scale;
      *(s16x4*)(outp + (((size_t)b * NH + hh) * NTOK + n) * HD + d) = cvt4(sc);
    }
    __syncthreads();
  }
}

// ---- K2: per-(window,head) attention, 8 waves, 2 q-tiles interleaved --------
// r3 structure (full K/V in LDS, barrier-free q-loop) + 2-stream ILP per wave
// to hide mask/bias L3 latency. K/V frags shared by both streams.
__global__ __launch_bounds__(512, 4)
void k_attn(const short* __restrict__ q_ws, const short* __restrict__ k_ws,
            const short* __restrict__ v_ws, const float* __restrict__ mask,
            const float* __restrict__ bias_pre, short* __restrict__ y_ws) {
  __shared__ short K_l[NKVP * KST];   // [kv][d]
  __shared__ short Vt[HD * VST];      // [d][kv]
  const int t = threadIdx.x;
  // XCD swizzle: 4 heads of one window land on the same XCD, adjacent slots
  const int j = blockIdx.x, xcd = j & 7, slot = j >> 3;
  const int b = (xcd << 5) | (slot >> 2);
  const int h = slot & 3;
  const size_t bh = (size_t)b * NH + h;
  const short* kp = k_ws + bh * NTOK * HD;
  const short* vp = v_ws + bh * NTOK * HD;
  const short* qp = q_ws + bh * NTOK * HD;
  const float* mp = mask + (size_t)b * NTOK * NTOK;
  const float* bp = bias_pre + (size_t)h * NTOK * NTOK;
  // stage K (+ zero pad rows)
  for (int r = t; r < NKVP; r += 512) {
    short* dst = K_l + r * KST;
    if (r < NTOK) {
      const s16x4* src = (const s16x4*)(kp + r * HD);
      #pragma unroll
      for (int i = 0; i < 8; ++i) *(s16x4*)(dst + 4*i) = src[i];
    } else {
      s16x4 zz = {0, 0, 0, 0};
      #pragma unroll
      for (int i = 0; i < 8; ++i) *(s16x4*)(dst + 4*i) = zz;
    }
  }
  // stage V transposed
  for (int n = t; n < NTOK; n += 512) {
    union { s16x4 v4[8]; short s[32]; } vv;
    const s16x4* src = (const s16x4*)(vp + n * HD);
    #pragma unroll
    for (int i = 0; i < 8; ++i) vv.v4[i] = src[i];
    #pragma unroll
    for (int d = 0; d < 32; ++d) Vt[d * VST + n] = vv.s[d];
  }
  // zero pad Vt cols [NTOK, VST)
  for (int i = t; i < HD * (VST - NTOK); i += 512) {
    int d = i / (VST - NTOK), c = NTOK + i % (VST - NTOK);
    Vt[d * VST + c] = 0;
  }
  __syncthreads();
  const int l = t & 63, w = t >> 6, lr = l & 15, g = l >> 4;
  const int og0 = 4 * g, og1 = 16 + 4 * g;
  #pragma unroll 1
  for (int pass = 0; pass < 2; ++pass) {
    const int T0 = w + pass * 16, T1 = T0 + 8;     // two tiles per wave
    const bool do1 = (T1 < 25);                    // wave-uniform
    const int qrowA = T0 * 16 + lr;                // always < NTOK (T0<=23)
    const int qrowB = T1 * 16 + lr;
    const int qcB = qrowB < NTOK ? qrowB : NTOK - 1;
    Frag qfA, qfB;
    { const short* qa = qp + qrowA * HD + 4 * g;
      qfA.h.lo = *(const s16x4*)qa; qfA.h.hi = *(const s16x4*)(qa + 16); }
    { const short* qa = qp + qcB * HD + 4 * g;
      qfB.h.lo = *(const s16x4*)qa; qfB.h.hi = *(const s16x4*)(qa + 16); }
    const float* mrowA = mp + (size_t)qrowA * NTOK;
    const float* browA = bp + (size_t)qrowA * NTOK;
    const float* mrowB = mp + (size_t)qcB * NTOK;
    const float* browB = bp + (size_t)qcB * NTOK;
    f32x4 oA0 = {0,0,0,0}, oA1 = {0,0,0,0}, oB0 = {0,0,0,0}, oB1 = {0,0,0,0};
    float mrunA = 0.f, nmrlA = 0.f, lrunA = 0.f;
    float mrunB = 0.f, nmrlB = 0.f, lrunB = 0.f;
    f32x4 mbA0, mbA1, mbB0, mbB1, nbA0, nbA1, nbB0, nbB1;
    load_mb(mrowA, browA, 0, og0, og1, g, mbA0, mbA1);
    if (do1) load_mb(mrowB, browB, 0, og0, og1, g, mbB0, mbB1);
    #pragma unroll 1
    for (int c = 0; c < NCH; ++c) {
      const int kv0 = c * 32;
      if (c < NCH - 1) {
        load_mb(mrowA, browA, c + 1, og0, og1, g, nbA0, nbA1);
        if (do1) load_mb(mrowB, browB, c + 1, og0, og1, g, nbB0, nbB1);
      }
      // K/V frags shared by both streams
      Frag ka0, ka1, vf0, vf1;
      { const short* p0 = K_l + (kv0 + lr) * KST + 4 * g;
        ka0.h.lo = *(const s16x4*)p0; ka0.h.hi = *(const s16x4*)(p0 + 16);
        const short* p1 = K_l + (kv0 + 16 + lr) * KST + 4 * g;
        ka1.h.lo = *(const s16x4*)p1; ka1.h.hi = *(const s16x4*)(p1 + 16);
        const short* v0 = Vt + lr * VST + kv0 + 4 * g;
        vf0.h.lo = *(const s16x4*)v0; vf0.h.hi = *(const s16x4*)(v0 + 16);
        const short* v1 = Vt + (16 + lr) * VST + kv0 + 4 * g;
        vf1.h.lo = *(const s16x4*)v1; vf1.h.hi = *(const s16x4*)(v1 + 16); }
      const f32x4 z4 = {0,0,0,0};
      // stream A
      f32x4 sA0 = __builtin_amdgcn_mfma_f32_16x16x32_bf16(ka0.v, qfA.v, z4, 0,0,0);
      f32x4 sA1 = __builtin_amdgcn_mfma_f32_16x16x32_bf16(ka1.v, qfA.v, z4, 0,0,0);
      sA0 += mbA0; sA1 += mbA1;
      sm_pv(sA0, sA1, oA0, oA1, mrunA, nmrlA, lrunA, vf0, vf1);
      // stream B
      if (do1) {
        f32x4 sB0 = __builtin_amdgcn_mfma_f32_16x16x32_bf16(ka0.v, qfB.v, z4, 0,0,0);
        f32x4 sB1 = __builtin_amdgcn_mfma_f32_16x16x32_bf16(ka1.v, qfB.v, z4, 0,0,0);
        sB0 += mbB0; sB1 += mbB1;
        sm_pv(sB0, sB1, oB0, oB1, mrunB, nmrlB, lrunB, vf0, vf1);
      }
      mbA0 = nbA0; mbA1 = nbA1;
      if (do1) { mbB0 = nbB0; mbB1 = nbB1; }
    }
    // combine per-lane partial sums across the 4 g-groups (once per tile)
    {
      float lt = lrunA + __shfl_xor(lrunA, 16);
      lt += __shfl_xor(lt, 32);
      const float inv = 1.0f / lt;
      short* yb = y_ws + ((size_t)b * NTOK + qrowA) * DIM + h * HD;
      s16x4 r0, r1;
      #pragma unroll
      for (int rr = 0; rr < 4; ++rr) { r0[rr] = f2bf(oA0[rr] * inv); r1[rr] = f2bf(oA1[rr] * inv); }
      *(s16x4*)(yb + 4 * g) = r0;
      *(s16x4*)(yb + 16 + 4 * g) = r1;
    }
    if (do1) {
      float lt = lrunB + __shfl_xor(lrunB, 16);
      lt += __shfl_xor(lt, 32);
      if (qrowB < NTOK) {
        const float inv = 1.0f / lt;
        short* yb = y_ws + ((size_t)b * NTOK + qrowB) * DIM + h * HD;
        s16x4 r0, r1;
        #pragma unroll
        for (int rr = 0; rr < 4; ++rr) { r0[rr] = f2bf(oB0[rr] * inv); r1[rr] = f2bf(oB1[rr] * inv); }
        *(s16x4*)(yb + 4 * g) = r0;
        *(s16x4*)(yb + 16 + 4 * g) = r1;
      }
    }
  }
}

// ---------------- K3: out = y @ proj_w^T + proj_b -----------------------------
__global__ __launch_bounds__(256, 2)
void k_proj(const short* __restrict__ y_ws, const float* __restrict__ pw,
            const float* __restrict__ pb, float* __restrict__ out) {
  __shared__ short ys[64 * 136];
  __shared__ short wl[128 * 136];
  const int t = threadIdx.x;
  const int m0 = blockIdx.x * 64;
  {
    const int r = t >> 2, c0 = (t & 3) * 32;
    const s16x4* src = (const s16x4*)(y_ws + (size_t)(m0 + r) * DIM + c0);
    short* dst = ys + r * 136 + c0;
    #pragma unroll
    for (int i = 0; i < 8; ++i) *(s16x4*)(dst + 4*i) = src[i];
  }
  {
    const int r = t >> 1, c0 = (t & 1) * 64;
    const float* src = pw + (size_t)r * DIM + c0;
    short* dst = wl + r * 136 + c0;
    #pragma unroll
    for (int i = 0; i < 16; ++i)
      *(s16x4*)(dst + 4*i) = cvt4(*(const f32x4*)(src + 4*i));
  }
  __syncthreads();
  const int l = t & 63, w = t >> 6, lr = l & 15, g = l >> 4;
  const int m = m0 + w * 16 + lr;
  f32x4 acc[8] = {};
  #pragma unroll
  for (int ks = 0; ks < 4; ++ks) {
    const int k0 = ks * 32 + 4 * g;
    Frag ya;
    const short* bp = ys + (w * 16 + lr) * 136 + k0;
    ya.h.lo = *(const s16x4*)bp; ya.h.hi = *(const s16x4*)(bp + 16);
    #pragma unroll
    for (int ct = 0; ct < 8; ++ct) {
      const short* ap = wl + (ct * 16 + lr) * 136 + k0;
      Frag wa; wa.h.lo = *(const s16x4*)ap; wa.h.hi = *(const s16x4*)(ap + 16);
      acc[ct] = __builtin_amdgcn_mfma_f32_16x16x32_bf16(wa.v, ya.v, acc[ct], 0, 0, 0);
    }
  }
  #pragma unroll
  for (int ct = 0; ct < 8; ++ct) {
    const int c0 = ct * 16 + 4 * g;
    const f32x4 pbv = *(const f32x4*)(pb + c0);
    f32x4 res = acc[ct] + pbv;
    *(f32x4*)(out + (size_t)m * DIM + c0) = res;
  }
}

extern "C" void kernel_launch(void* const* d_in, const int* in_sizes, int n_in,
                              void* d_out, int out_size, void* d_ws, size_t ws_size,
                              hipStream_t stream) {
  const float* x    = (const float*)d_in[0];
  const float* mask = (const float*)d_in[1];
  const float* bt   = (const float*)d_in[2];
  const int*   ri   = (const int*)d_in[3];
  const float* qkvw = (const float*)d_in[4];
  const float* pw   = (const float*)d_in[5];
  const float* pb   = (const float*)d_in[6];
  float* out = (float*)d_out;
  // ws layout: 4 x 25.69MB bf16 tensors + 2.46MB f32 bias = ~105.2MB
  const size_t TEN = (size_t)256 * NH * NTOK * HD;   // 12,845,056
  short* q_ws = (short*)d_ws;
  short* k_ws = q_ws + TEN;
  short* v_ws = k_ws + TEN;
  short* y_ws = v_ws + TEN;
  float* bias_pre = (float*)(y_ws + TEN);
  k_bias<<<(NTOK * NTOK + 255) / 256, 256, 0, stream>>>(bt, ri, bias_pre);
  k_qkv<<<1568, 256, 0, stream>>>(x, qkvw, q_ws, k_ws, v_ws);
  k_attn<<<1024, 512, 0, stream>>>(q_ws, k_ws, v_ws, mask, bias_pre, y_ws);
  k_proj<<<1568, 256, 0, stream>>>(y_ws, pw, pb, out);
}

// Round 6
// 224.267 us; speedup vs baseline: 1.9778x; 1.1762x over previous
//
#include <hip/hip_runtime.h>
#include <hip/hip_bf16.h>
#include <stdint.h>

#define NTOK 392
#define DIM  128
#define NH   4
#define HD   32
#define NKVP 416   // 13*32 padded keys
#define NCH  13
#define KST  36    // K_lds stride (shorts): 18*r mod 32 distinct -> conflict-free
#define VST  420   // Vt_lds stride (shorts): 210 dwords; 18d mod 32 distinct
#define L2E  1.44269504f
#define BPQ  416   // bias_perm shorts per q-row (13*32)

typedef __attribute__((ext_vector_type(4))) float f32x4;
typedef __attribute__((ext_vector_type(4))) short s16x4;
typedef __attribute__((ext_vector_type(8))) short s16x8;

union Frag { s16x8 v; struct { s16x4 lo, hi; } h; };
union PF { s16x8 v; uint32_t u[4]; };

__device__ __forceinline__ short f2bf(float f) {
  union { float f; uint32_t u; } v; v.f = f;
  uint32_t r = v.u + 0x7fffu + ((v.u >> 16) & 1u);
  return (short)(r >> 16);
}
__device__ __forceinline__ s16x4 cvt4(f32x4 a) {
  s16x4 r; r.x = f2bf(a.x); r.y = f2bf(a.y); r.z = f2bf(a.z); r.w = f2bf(a.w);
  return r;
}
// bf16x8 -> 2x f32x4 (2 VALU per dword: shl16 / and-hi)
__device__ __forceinline__ void bb2f(s16x8 b, f32x4& lo, f32x4& hi) {
  union { s16x8 s; uint32_t u[4]; } x; x.s = b;
  union { uint32_t u; float f; } t;
  t.u = x.u[0] << 16;          lo.x = t.f;
  t.u = x.u[0] & 0xffff0000u;  lo.y = t.f;
  t.u = x.u[1] << 16;          lo.z = t.f;
  t.u = x.u[1] & 0xffff0000u;  lo.w = t.f;
  t.u = x.u[2] << 16;          hi.x = t.f;
  t.u = x.u[2] & 0xffff0000u;  hi.y = t.f;
  t.u = x.u[3] << 16;          hi.z = t.f;
  t.u = x.u[3] & 0xffff0000u;  hi.w = t.f;
}

// online-softmax + PV step (verified r3 body)
__device__ __forceinline__ void sm_pv(f32x4 s0, f32x4 s1,
                                      f32x4& o0, f32x4& o1,
                                      float& mrun, float& nmrl, float& lrun,
                                      const Frag& vf0, const Frag& vf1) {
  float cm = fmaxf(fmaxf(fmaxf(s0.x, s0.y), fmaxf(s0.z, s0.w)),
                   fmaxf(fmaxf(s1.x, s1.y), fmaxf(s1.z, s1.w)));
  if (__any(cm > mrun + 8.f)) {         // rare: true running-max rescale
    float tmx = fmaxf(cm, __shfl_xor(cm, 16));
    tmx = fmaxf(tmx, __shfl_xor(tmx, 32));
    const float mnew = fmaxf(mrun, tmx);
    const float al = exp2f((mrun - mnew) * L2E);
    #pragma unroll
    for (int rr = 0; rr < 4; ++rr) { o0[rr] *= al; o1[rr] *= al; }
    lrun *= al; mrun = mnew; nmrl = -mnew * L2E;
  }
  float p0 = exp2f(fmaf(s0.x, L2E, nmrl));
  float p1 = exp2f(fmaf(s0.y, L2E, nmrl));
  float p2 = exp2f(fmaf(s0.z, L2E, nmrl));
  float p3 = exp2f(fmaf(s0.w, L2E, nmrl));
  float p4 = exp2f(fmaf(s1.x, L2E, nmrl));
  float p5 = exp2f(fmaf(s1.y, L2E, nmrl));
  float p6 = exp2f(fmaf(s1.z, L2E, nmrl));
  float p7 = exp2f(fmaf(s1.w, L2E, nmrl));
  lrun += ((p0 + p1) + (p2 + p3)) + ((p4 + p5) + (p6 + p7));
  PF pf;
  asm("v_cvt_pk_bf16_f32 %0, %1, %2" : "=v"(pf.u[0]) : "v"(p0), "v"(p1));
  asm("v_cvt_pk_bf16_f32 %0, %1, %2" : "=v"(pf.u[1]) : "v"(p2), "v"(p3));
  asm("v_cvt_pk_bf16_f32 %0, %1, %2" : "=v"(pf.u[2]) : "v"(p4), "v"(p5));
  asm("v_cvt_pk_bf16_f32 %0, %1, %2" : "=v"(pf.u[3]) : "v"(p6), "v"(p7));
  o0 = __builtin_amdgcn_mfma_f32_16x16x32_bf16(vf0.v, pf.v, o0, 0, 0, 0);
  o1 = __builtin_amdgcn_mfma_f32_16x16x32_bf16(vf1.v, pf.v, o1, 0, 0, 0);
}

// ---- K0: bias -> frag-ordered bf16 [h][q][c][g][hb][j], pad kv poisoned ----
__global__ void k_biasperm(const float* __restrict__ bt, const int* __restrict__ ri,
                           short* __restrict__ bias_perm) {
  int i = blockIdx.x * 256 + threadIdx.x;
  if (i >= NH * NTOK * BPQ) return;
  int h = i / (NTOK * BPQ);
  int r = i - h * (NTOK * BPQ);
  int q = r / BPQ;
  int p = r - q * BPQ;               // c*32 + g*8 + hb*4 + j
  int c = p >> 5, w2 = p & 31;
  int g = w2 >> 3, hb = (w2 >> 2) & 1, jj = w2 & 3;
  int kv = c * 32 + hb * 16 + g * 4 + jj;
  float v = -3e30f;
  if (kv < NTOK) v = bt[ri[q * NTOK + kv] * NH + h];
  bias_perm[i] = f2bf(v);
}

// ------- K1: qkv = x @ qkv_w^T, bf16 out, q pre-scaled; fused z-loop ---------
__global__ __launch_bounds__(256, 2)
void k_qkv(const float* __restrict__ x, const float* __restrict__ qkv_w,
           short* __restrict__ q_ws, short* __restrict__ k_ws,
           short* __restrict__ v_ws) {
  __shared__ short xs[64 * 136];
  __shared__ short wl[128 * 136];
  const int t  = threadIdx.x;
  const int m0 = blockIdx.x * 64;
  {
    const int r = t >> 2, c0 = (t & 3) * 32;
    const float* src = x + (size_t)(m0 + r) * DIM + c0;
    short* dst = xs + r * 136 + c0;
    #pragma unroll
    for (int i = 0; i < 8; ++i)
      *(s16x4*)(dst + 4*i) = cvt4(*(const f32x4*)(src + 4*i));
  }
  const int l = t & 63, w = t >> 6, lr = l & 15, g = l >> 4;
  const int m = m0 + w * 16 + lr;
  const int b = m / NTOK;
  const int n = m - b * NTOK;
  #pragma unroll 1
  for (int z = 0; z < 3; ++z) {
    {
      const int r = t >> 1, c0 = (t & 1) * 64;
      const float* src = qkv_w + (size_t)(z * DIM + r) * DIM + c0;
      short* dst = wl + r * 136 + c0;
      #pragma unroll
      for (int i = 0; i < 16; ++i)
        *(s16x4*)(dst + 4*i) = cvt4(*(const f32x4*)(src + 4*i));
    }
    __syncthreads();
    f32x4 acc[8] = {};
    #pragma unroll
    for (int ks = 0; ks < 4; ++ks) {
      const int k0 = ks * 32 + 4 * g;
      Frag xb;
      const short* bp = xs + (w * 16 + lr) * 136 + k0;
      xb.h.lo = *(const s16x4*)bp; xb.h.hi = *(const s16x4*)(bp + 16);
      #pragma unroll
      for (int ct = 0; ct < 8; ++ct) {
        const short* ap = wl + (ct * 16 + lr) * 136 + k0;
        Frag wa; wa.h.lo = *(const s16x4*)ap; wa.h.hi = *(const s16x4*)(ap + 16);
        acc[ct] = __builtin_amdgcn_mfma_f32_16x16x32_bf16(wa.v, xb.v, acc[ct], 0, 0, 0);
      }
    }
    short* outp = (z == 0) ? q_ws : (z == 1 ? k_ws : v_ws);
    const float scale = (z == 0) ? 0.17677669529663689f : 1.0f;
    #pragma unroll
    for (int ct = 0; ct < 8; ++ct) {
      const int c0 = ct * 16 + 4 * g;       // 4 consecutive channels
      const int hh = c0 >> 5, d = c0 & 31;
      f32x4 sc = acc[ct];
      sc.x *= scale; sc.y *= scale; sc.z *= scale; sc.w *= scale;
      *(s16x4*)(outp + (((size_t)b * NH + hh) * NTOK + n) * HD + d) = cvt4(sc);
    }
    __syncthreads();
  }
}

// ---- K2: per-(window,head) attention, single stream, unrolled chunks, ------
// ---- distance-2 raw-register prefetch of mask(f32)+bias(bf16-perm) ---------
__global__ __launch_bounds__(512, 4)
void k_attn(const short* __restrict__ q_ws, const short* __restrict__ k_ws,
            const short* __restrict__ v_ws, const float* __restrict__ mask,
            const short* __restrict__ bias_perm, short* __restrict__ y_ws) {
  __shared__ short K_l[NKVP * KST];   // [kv][d]
  __shared__ short Vt[HD * VST];      // [d][kv]
  const int t = threadIdx.x;
  // XCD swizzle: 4 heads of one window land on the same XCD, adjacent slots
  const int j = blockIdx.x, xcd = j & 7, slot = j >> 3;
  const int b = (xcd << 5) | (slot >> 2);
  const int h = slot & 3;
  const size_t bh = (size_t)b * NH + h;
  const short* kp = k_ws + bh * NTOK * HD;
  const short* vp = v_ws + bh * NTOK * HD;
  const short* qp = q_ws + bh * NTOK * HD;
  const float* mp = mask + (size_t)b * NTOK * NTOK;
  const short* bph = bias_perm + (size_t)h * NTOK * BPQ;
  // stage K (+ zero pad rows)
  for (int r = t; r < NKVP; r += 512) {
    short* dst = K_l + r * KST;
    if (r < NTOK) {
      const s16x4* src = (const s16x4*)(kp + r * HD);
      #pragma unroll
      for (int i = 0; i < 8; ++i) *(s16x4*)(dst + 4*i) = src[i];
    } else {
      s16x4 zz = {0, 0, 0, 0};
      #pragma unroll
      for (int i = 0; i < 8; ++i) *(s16x4*)(dst + 4*i) = zz;
    }
  }
  // stage V transposed
  for (int n = t; n < NTOK; n += 512) {
    union { s16x4 v4[8]; short s[32]; } vv;
    const s16x4* src = (const s16x4*)(vp + n * HD);
    #pragma unroll
    for (int i = 0; i < 8; ++i) vv.v4[i] = src[i];
    #pragma unroll
    for (int d = 0; d < 32; ++d) Vt[d * VST + n] = vv.s[d];
  }
  // zero pad Vt cols [NTOK, VST)
  for (int i = t; i < HD * (VST - NTOK); i += 512) {
    int d = i / (VST - NTOK), c = NTOK + i % (VST - NTOK);
    Vt[d * VST + c] = 0;
  }
  __syncthreads();
  const int l = t & 63, w = t >> 6, lr = l & 15, g = l >> 4;
  const int og0 = 4 * g, og1 = 16 + 4 * g;
  #pragma unroll 1
  for (int q0 = w * 16; q0 < NTOK; q0 += 128) {
    const int qrow = q0 + lr;
    const int qc = qrow < NTOK ? qrow : NTOK - 1;
    Frag qf;
    { const short* qa = qp + qc * HD + 4 * g;
      qf.h.lo = *(const s16x4*)qa; qf.h.hi = *(const s16x4*)(qa + 16); }
    const float* mrow = mp + (size_t)qc * NTOK;
    const short* brow = bph + qc * BPQ;
    f32x4 mm0[3], mm1[3];   // raw mask slots (no arithmetic at issue!)
    s16x8 bb[3];            // raw bias slots (bf16, poison baked in)
    #pragma unroll
    for (int c = 0; c < 2; ++c) {
      mm0[c] = *(const f32x4*)(mrow + c * 32 + og0);
      mm1[c] = *(const f32x4*)(mrow + c * 32 + og1);
      bb[c]  = *(const s16x8*)(brow + c * 32 + g * 8);
    }
    f32x4 o0 = {0,0,0,0}, o1 = {0,0,0,0};
    float mrun = 0.f, nmrl = 0.f, lrun = 0.f;
    #pragma unroll
    for (int c = 0; c < NCH; ++c) {
      const int sl = c % 3;             // static after unroll
      if (c + 2 < NCH) {
        const int cc = c + 2, s2 = (c + 2) % 3;
        int a0 = cc * 32 + og0, a1 = cc * 32 + og1;
        if (cc == NCH - 1) { a0 = a0 > 388 ? 388 : a0; a1 = 388; }  // no OOB; poisoned via bias
        mm0[s2] = *(const f32x4*)(mrow + a0);
        mm1[s2] = *(const f32x4*)(mrow + a1);
        bb[s2]  = *(const s16x8*)(brow + cc * 32 + g * 8);
      }
      const int kv0 = c * 32;
      Frag ka0, ka1, vf0, vf1;
      { const short* p0 = K_l + (kv0 + lr) * KST + 4 * g;
        ka0.h.lo = *(const s16x4*)p0; ka0.h.hi = *(const s16x4*)(p0 + 16);
        const short* p1 = K_l + (kv0 + 16 + lr) * KST + 4 * g;
        ka1.h.lo = *(const s16x4*)p1; ka1.h.hi = *(const s16x4*)(p1 + 16);
        const short* v0 = Vt + lr * VST + kv0 + 4 * g;
        vf0.h.lo = *(const s16x4*)v0; vf0.h.hi = *(const s16x4*)(v0 + 16);
        const short* v1 = Vt + (16 + lr) * VST + kv0 + 4 * g;
        vf1.h.lo = *(const s16x4*)v1; vf1.h.hi = *(const s16x4*)(v1 + 16); }
      const f32x4 z4 = {0,0,0,0};
      f32x4 s0 = __builtin_amdgcn_mfma_f32_16x16x32_bf16(ka0.v, qf.v, z4, 0,0,0);
      f32x4 s1 = __builtin_amdgcn_mfma_f32_16x16x32_bf16(ka1.v, qf.v, z4, 0,0,0);
      f32x4 blo, bhi;
      bb2f(bb[sl], blo, bhi);           // converts + poison at USE time
      s0 += mm0[sl] + blo;
      s1 += mm1[sl] + bhi;
      sm_pv(s0, s1, o0, o1, mrun, nmrl, lrun, vf0, vf1);
    }
    float lt = lrun + __shfl_xor(lrun, 16);
    lt += __shfl_xor(lt, 32);
    if (qrow < NTOK) {
      const float inv = 1.0f / lt;
      short* yb = y_ws + ((size_t)b * NTOK + qrow) * DIM + h * HD;
      s16x4 r0, r1;
      #pragma unroll
      for (int rr = 0; rr < 4; ++rr) { r0[rr] = f2bf(o0[rr] * inv); r1[rr] = f2bf(o1[rr] * inv); }
      *(s16x4*)(yb + 4 * g) = r0;
      *(s16x4*)(yb + 16 + 4 * g) = r1;
    }
  }
}

// ---------------- K3: out = y @ proj_w^T + proj_b -----------------------------
__global__ __launch_bounds__(256, 2)
void k_proj(const short* __restrict__ y_ws, const float* __restrict__ pw,
            const float* __restrict__ pb, float* __restrict__ out) {
  __shared__ short ys[64 * 136];
  __shared__ short wl[128 * 136];
  const int t = threadIdx.x;
  const int m0 = blockIdx.x * 64;
  {
    const int r = t >> 2, c0 = (t & 3) * 32;
    const s16x4* src = (const s16x4*)(y_ws + (size_t)(m0 + r) * DIM + c0);
    short* dst = ys + r * 136 + c0;
    #pragma unroll
    for (int i = 0; i < 8; ++i) *(s16x4*)(dst + 4*i) = src[i];
  }
  {
    const int r = t >> 1, c0 = (t & 1) * 64;
    const float* src = pw + (size_t)r * DIM + c0;
    short* dst = wl + r * 136 + c0;
    #pragma unroll
    for (int i = 0; i < 16; ++i)
      *(s16x4*)(dst + 4*i) = cvt4(*(const f32x4*)(src + 4*i));
  }
  __syncthreads();
  const int l = t & 63, w = t >> 6, lr = l & 15, g = l >> 4;
  const int m = m0 + w * 16 + lr;
  f32x4 acc[8] = {};
  #pragma unroll
  for (int ks = 0; ks < 4; ++ks) {
    const int k0 = ks * 32 + 4 * g;
    Frag ya;
    const short* bp = ys + (w * 16 + lr) * 136 + k0;
    ya.h.lo = *(const s16x4*)bp; ya.h.hi = *(const s16x4*)(bp + 16);
    #pragma unroll
    for (int ct = 0; ct < 8; ++ct) {
      const short* ap = wl + (ct * 16 + lr) * 136 + k0;
      Frag wa; wa.h.lo = *(const s16x4*)ap; wa.h.hi = *(const s16x4*)(ap + 16);
      acc[ct] = __builtin_amdgcn_mfma_f32_16x16x32_bf16(wa.v, ya.v, acc[ct], 0, 0, 0);
    }
  }
  #pragma unroll
  for (int ct = 0; ct < 8; ++ct) {
    const int c0 = ct * 16 + 4 * g;
    const f32x4 pbv = *(const f32x4*)(pb + c0);
    f32x4 res = acc[ct] + pbv;
    *(f32x4*)(out + (size_t)m * DIM + c0) = res;
  }
}

extern "C" void kernel_launch(void* const* d_in, const int* in_sizes, int n_in,
                              void* d_out, int out_size, void* d_ws, size_t ws_size,
                              hipStream_t stream) {
  const float* x    = (const float*)d_in[0];
  const float* mask = (const float*)d_in[1];
  const float* bt   = (const float*)d_in[2];
  const int*   ri   = (const int*)d_in[3];
  const float* qkvw = (const float*)d_in[4];
  const float* pw   = (const float*)d_in[5];
  const float* pb   = (const float*)d_in[6];
  float* out = (float*)d_out;
  // ws layout: 4 x 25.69MB bf16 tensors + 1.3MB bf16 bias_perm = ~104MB
  const size_t TEN = (size_t)256 * NH * NTOK * HD;   // 12,845,056
  short* q_ws = (short*)d_ws;
  short* k_ws = q_ws + TEN;
  short* v_ws = k_ws + TEN;
  short* y_ws = v_ws + TEN;
  short* bias_perm = y_ws + TEN;                     // NH*NTOK*BPQ shorts
  k_biasperm<<<(NH * NTOK * BPQ + 255) / 256, 256, 0, stream>>>(bt, ri, bias_perm);
  k_qkv<<<1568, 256, 0, stream>>>(x, qkvw, q_ws, k_ws, v_ws);
  k_attn<<<1024, 512, 0, stream>>>(q_ws, k_ws, v_ws, mask, bias_perm, y_ws);
  k_proj<<<1568, 256, 0, stream>>>(y_ws, pw, pb, out);
}

// Round 8
// 202.933 us; speedup vs baseline: 2.1857x; 1.1051x over previous
//
#include <hip/hip_runtime.h>
#include <hip/hip_bf16.h>
#include <stdint.h>

#define NTOK 392
#define DIM  128
#define NH   4
#define HD   32
#define NKVP 416   // 13*32 padded keys
#define NCH  13
#define KST  36    // K_lds stride (shorts): measured conflict-free
#define VST  420   // Vt_lds stride (shorts): measured conflict-free
#define L2E  1.44269504f
#define BPQ  416   // bias_perm shorts per q-row (13*32)

typedef __attribute__((ext_vector_type(4))) float f32x4;
typedef __attribute__((ext_vector_type(4))) short s16x4;
typedef __attribute__((ext_vector_type(8))) short s16x8;

union Frag { s16x8 v; struct { s16x4 lo, hi; } h; };
union PF { s16x8 v; uint32_t u[4]; };

__device__ __forceinline__ short f2bf(float f) {
  union { float f; uint32_t u; } v; v.f = f;
  uint32_t r = v.u + 0x7fffu + ((v.u >> 16) & 1u);
  return (short)(r >> 16);
}
__device__ __forceinline__ s16x4 cvt4(f32x4 a) {
  s16x4 r; r.x = f2bf(a.x); r.y = f2bf(a.y); r.z = f2bf(a.z); r.w = f2bf(a.w);
  return r;
}
// bf16x8 -> 2x f32x4 (2 VALU per dword: shl16 / and-hi)
__device__ __forceinline__ void bb2f(s16x8 b, f32x4& lo, f32x4& hi) {
  union { s16x8 s; uint32_t u[4]; } x; x.s = b;
  union { uint32_t u; float f; } t;
  t.u = x.u[0] << 16;          lo.x = t.f;
  t.u = x.u[0] & 0xffff0000u;  lo.y = t.f;
  t.u = x.u[1] << 16;          lo.z = t.f;
  t.u = x.u[1] & 0xffff0000u;  lo.w = t.f;
  t.u = x.u[2] << 16;          hi.x = t.f;
  t.u = x.u[2] & 0xffff0000u;  hi.y = t.f;
  t.u = x.u[3] << 16;          hi.z = t.f;
  t.u = x.u[3] & 0xffff0000u;  hi.w = t.f;
}

// online-softmax + PV step (verified r3 body)
__device__ __forceinline__ void sm_pv(f32x4 s0, f32x4 s1,
                                      f32x4& o0, f32x4& o1,
                                      float& mrun, float& nmrl, float& lrun,
                                      const Frag& vf0, const Frag& vf1) {
  float cm = fmaxf(fmaxf(fmaxf(s0.x, s0.y), fmaxf(s0.z, s0.w)),
                   fmaxf(fmaxf(s1.x, s1.y), fmaxf(s1.z, s1.w)));
  if (__any(cm > mrun + 8.f)) {         // rare: true running-max rescale
    float tmx = fmaxf(cm, __shfl_xor(cm, 16));
    tmx = fmaxf(tmx, __shfl_xor(tmx, 32));
    const float mnew = fmaxf(mrun, tmx);
    const float al = exp2f((mrun - mnew) * L2E);
    #pragma unroll
    for (int rr = 0; rr < 4; ++rr) { o0[rr] *= al; o1[rr] *= al; }
    lrun *= al; mrun = mnew; nmrl = -mnew * L2E;
  }
  float p0 = exp2f(fmaf(s0.x, L2E, nmrl));
  float p1 = exp2f(fmaf(s0.y, L2E, nmrl));
  float p2 = exp2f(fmaf(s0.z, L2E, nmrl));
  float p3 = exp2f(fmaf(s0.w, L2E, nmrl));
  float p4 = exp2f(fmaf(s1.x, L2E, nmrl));
  float p5 = exp2f(fmaf(s1.y, L2E, nmrl));
  float p6 = exp2f(fmaf(s1.z, L2E, nmrl));
  float p7 = exp2f(fmaf(s1.w, L2E, nmrl));
  lrun += ((p0 + p1) + (p2 + p3)) + ((p4 + p5) + (p6 + p7));
  PF pf;
  asm("v_cvt_pk_bf16_f32 %0, %1, %2" : "=v"(pf.u[0]) : "v"(p0), "v"(p1));
  asm("v_cvt_pk_bf16_f32 %0, %1, %2" : "=v"(pf.u[1]) : "v"(p2), "v"(p3));
  asm("v_cvt_pk_bf16_f32 %0, %1, %2" : "=v"(pf.u[2]) : "v"(p4), "v"(p5));
  asm("v_cvt_pk_bf16_f32 %0, %1, %2" : "=v"(pf.u[3]) : "v"(p6), "v"(p7));
  o0 = __builtin_amdgcn_mfma_f32_16x16x32_bf16(vf0.v, pf.v, o0, 0, 0, 0);
  o1 = __builtin_amdgcn_mfma_f32_16x16x32_bf16(vf1.v, pf.v, o1, 0, 0, 0);
}

// ---- K0a: bias -> frag-ordered bf16 [h][q][c][g][hb][j], pad kv poisoned ----
__global__ void k_biasperm(const float* __restrict__ bt, const int* __restrict__ ri,
                           short* __restrict__ bias_perm) {
  int i = blockIdx.x * 256 + threadIdx.x;
  if (i >= NH * NTOK * BPQ) return;
  int h = i / (NTOK * BPQ);
  int r = i - h * (NTOK * BPQ);
  int q = r / BPQ;
  int p = r - q * BPQ;               // c*32 + g*8 + hb*4 + j
  int c = p >> 5, w2 = p & 31;
  int g = w2 >> 3, hb = (w2 >> 2) & 1, jj = w2 & 3;
  int kv = c * 32 + hb * 16 + g * 4 + jj;
  float v = -3e30f;
  if (kv < NTOK) v = bt[ri[q * NTOK + kv] * NH + h];
  bias_perm[i] = f2bf(v);
}

// ---- K0b: weights -> bf16 (one-time; kills per-block cvt in K1/K3) ---------
__global__ void k_wprep(const float* __restrict__ qkvw, const float* __restrict__ pw,
                        short* __restrict__ wq_bf, short* __restrict__ wp_bf) {
  int i = blockIdx.x * 256 + threadIdx.x;
  if (i < 3 * DIM * DIM) wq_bf[i] = f2bf(qkvw[i]);
  if (i < DIM * DIM)     wp_bf[i] = f2bf(pw[i]);
}

// ------- K1: qkv = x @ qkv_w^T, bf16 out, q pre-scaled; fused z-loop ---------
__global__ __launch_bounds__(256, 2)
void k_qkv(const float* __restrict__ x, const short* __restrict__ wq_bf,
           short* __restrict__ q_ws, short* __restrict__ k_ws,
           short* __restrict__ v_ws) {
  __shared__ short xs[64 * 136];
  __shared__ short wl[128 * 136];
  const int t  = threadIdx.x;
  const int m0 = blockIdx.x * 64;
  {
    const int r = t >> 2, c0 = (t & 3) * 32;
    const float* src = x + (size_t)(m0 + r) * DIM + c0;
    short* dst = xs + r * 136 + c0;
    #pragma unroll
    for (int i = 0; i < 8; ++i)
      *(s16x4*)(dst + 4*i) = cvt4(*(const f32x4*)(src + 4*i));
  }
  const int l = t & 63, w = t >> 6, lr = l & 15, g = l >> 4;
  const int m = m0 + w * 16 + lr;
  const int b = m / NTOK;
  const int n = m - b * NTOK;
  #pragma unroll 1
  for (int z = 0; z < 3; ++z) {
    {
      const int r = t >> 1, c0 = (t & 1) * 64;
      const short* src = wq_bf + (size_t)(z * DIM + r) * DIM + c0;
      short* dst = wl + r * 136 + c0;
      #pragma unroll
      for (int i = 0; i < 8; ++i)
        *(s16x8*)(dst + 8*i) = *(const s16x8*)(src + 8*i);
    }
    __syncthreads();
    f32x4 acc[8] = {};
    #pragma unroll
    for (int ks = 0; ks < 4; ++ks) {
      const int k0 = ks * 32 + 4 * g;
      Frag xb;
      const short* bp = xs + (w * 16 + lr) * 136 + k0;
      xb.h.lo = *(const s16x4*)bp; xb.h.hi = *(const s16x4*)(bp + 16);
      #pragma unroll
      for (int ct = 0; ct < 8; ++ct) {
        const short* ap = wl + (ct * 16 + lr) * 136 + k0;
        Frag wa; wa.h.lo = *(const s16x4*)ap; wa.h.hi = *(const s16x4*)(ap + 16);
        acc[ct] = __builtin_amdgcn_mfma_f32_16x16x32_bf16(wa.v, xb.v, acc[ct], 0, 0, 0);
      }
    }
    short* outp = (z == 0) ? q_ws : (z == 1 ? k_ws : v_ws);
    const float scale = (z == 0) ? 0.17677669529663689f : 1.0f;
    #pragma unroll
    for (int ct = 0; ct < 8; ++ct) {
      const int c0 = ct * 16 + 4 * g;       // 4 consecutive channels
      const int hh = c0 >> 5, d = c0 & 31;
      f32x4 sc = acc[ct];
      sc.x *= scale; sc.y *= scale; sc.z *= scale; sc.w *= scale;
      *(s16x4*)(outp + (((size_t)b * NH + hh) * NTOK + n) * HD + d) = cvt4(sc);
    }
    __syncthreads();
  }
}

// ---- K2: per-(window,head) attention, single stream, unrolled chunks, ------
// ---- distance-2 raw-register prefetch of mask(f32)+bias(bf16-perm) ---------
// ---- (r6-verified body, byte-identical) ------------------------------------
__global__ __launch_bounds__(512, 4)
void k_attn(const short* __restrict__ q_ws, const short* __restrict__ k_ws,
            const short* __restrict__ v_ws, const float* __restrict__ mask,
            const short* __restrict__ bias_perm, short* __restrict__ y_ws) {
  __shared__ short K_l[NKVP * KST];   // [kv][d]
  __shared__ short Vt[HD * VST];      // [d][kv]
  const int t = threadIdx.x;
  // XCD swizzle: 4 heads of one window land on the same XCD, adjacent slots
  const int j = blockIdx.x, xcd = j & 7, slot = j >> 3;
  const int b = (xcd << 5) | (slot >> 2);
  const int h = slot & 3;
  const size_t bh = (size_t)b * NH + h;
  const short* kp = k_ws + bh * NTOK * HD;
  const short* vp = v_ws + bh * NTOK * HD;
  const short* qp = q_ws + bh * NTOK * HD;
  const float* mp = mask + (size_t)b * NTOK * NTOK;
  const short* bph = bias_perm + (size_t)h * NTOK * BPQ;
  // stage K (+ zero pad rows)
  for (int r = t; r < NKVP; r += 512) {
    short* dst = K_l + r * KST;
    if (r < NTOK) {
      const s16x4* src = (const s16x4*)(kp + r * HD);
      #pragma unroll
      for (int i = 0; i < 8; ++i) *(s16x4*)(dst + 4*i) = src[i];
    } else {
      s16x4 zz = {0, 0, 0, 0};
      #pragma unroll
      for (int i = 0; i < 8; ++i) *(s16x4*)(dst + 4*i) = zz;
    }
  }
  // stage V transposed
  for (int n = t; n < NTOK; n += 512) {
    union { s16x4 v4[8]; short s[32]; } vv;
    const s16x4* src = (const s16x4*)(vp + n * HD);
    #pragma unroll
    for (int i = 0; i < 8; ++i) vv.v4[i] = src[i];
    #pragma unroll
    for (int d = 0; d < 32; ++d) Vt[d * VST + n] = vv.s[d];
  }
  // zero pad Vt cols [NTOK, VST)
  for (int i = t; i < HD * (VST - NTOK); i += 512) {
    int d = i / (VST - NTOK), c = NTOK + i % (VST - NTOK);
    Vt[d * VST + c] = 0;
  }
  __syncthreads();
  const int l = t & 63, w = t >> 6, lr = l & 15, g = l >> 4;
  const int og0 = 4 * g, og1 = 16 + 4 * g;
  #pragma unroll 1
  for (int q0 = w * 16; q0 < NTOK; q0 += 128) {
    const int qrow = q0 + lr;
    const int qc = qrow < NTOK ? qrow : NTOK - 1;
    Frag qf;
    { const short* qa = qp + qc * HD + 4 * g;
      qf.h.lo = *(const s16x4*)qa; qf.h.hi = *(const s16x4*)(qa + 16); }
    const float* mrow = mp + (size_t)qc * NTOK;
    const short* brow = bph + qc * BPQ;
    f32x4 mm0[3], mm1[3];   // raw mask slots (no arithmetic at issue!)
    s16x8 bb[3];            // raw bias slots (bf16, poison baked in)
    #pragma unroll
    for (int c = 0; c < 2; ++c) {
      mm0[c] = *(const f32x4*)(mrow + c * 32 + og0);
      mm1[c] = *(const f32x4*)(mrow + c * 32 + og1);
      bb[c]  = *(const s16x8*)(brow + c * 32 + g * 8);
    }
    f32x4 o0 = {0,0,0,0}, o1 = {0,0,0,0};
    float mrun = 0.f, nmrl = 0.f, lrun = 0.f;
    #pragma unroll
    for (int c = 0; c < NCH; ++c) {
      const int sl = c % 3;             // static after unroll
      if (c + 2 < NCH) {
        const int cc = c + 2, s2 = (c + 2) % 3;
        int a0 = cc * 32 + og0, a1 = cc * 32 + og1;
        if (cc == NCH - 1) { a0 = a0 > 388 ? 388 : a0; a1 = 388; }  // no OOB; poisoned via bias
        mm0[s2] = *(const f32x4*)(mrow + a0);
        mm1[s2] = *(const f32x4*)(mrow + a1);
        bb[s2]  = *(const s16x8*)(brow + cc * 32 + g * 8);
      }
      const int kv0 = c * 32;
      Frag ka0, ka1, vf0, vf1;
      { const short* p0 = K_l + (kv0 + lr) * KST + 4 * g;
        ka0.h.lo = *(const s16x4*)p0; ka0.h.hi = *(const s16x4*)(p0 + 16);
        const short* p1 = K_l + (kv0 + 16 + lr) * KST + 4 * g;
        ka1.h.lo = *(const s16x4*)p1; ka1.h.hi = *(const s16x4*)(p1 + 16);
        const short* v0 = Vt + lr * VST + kv0 + 4 * g;
        vf0.h.lo = *(const s16x4*)v0; vf0.h.hi = *(const s16x4*)(v0 + 16);
        const short* v1 = Vt + (16 + lr) * VST + kv0 + 4 * g;
        vf1.h.lo = *(const s16x4*)v1; vf1.h.hi = *(const s16x4*)(v1 + 16); }
      const f32x4 z4 = {0,0,0,0};
      f32x4 s0 = __builtin_amdgcn_mfma_f32_16x16x32_bf16(ka0.v, qf.v, z4, 0,0,0);
      f32x4 s1 = __builtin_amdgcn_mfma_f32_16x16x32_bf16(ka1.v, qf.v, z4, 0,0,0);
      f32x4 blo, bhi;
      bb2f(bb[sl], blo, bhi);           // converts + poison at USE time
      s0 += mm0[sl] + blo;
      s1 += mm1[sl] + bhi;
      sm_pv(s0, s1, o0, o1, mrun, nmrl, lrun, vf0, vf1);
    }
    float lt = lrun + __shfl_xor(lrun, 16);
    lt += __shfl_xor(lt, 32);
    if (qrow < NTOK) {
      const float inv = 1.0f / lt;
      short* yb = y_ws + ((size_t)b * NTOK + qrow) * DIM + h * HD;
      s16x4 r0, r1;
      #pragma unroll
      for (int rr = 0; rr < 4; ++rr) { r0[rr] = f2bf(o0[rr] * inv); r1[rr] = f2bf(o1[rr] * inv); }
      *(s16x4*)(yb + 4 * g) = r0;
      *(s16x4*)(yb + 16 + 4 * g) = r1;
    }
  }
}

// ---------------- K3: out = y @ proj_w^T + proj_b -----------------------------
__global__ __launch_bounds__(256, 2)
void k_proj(const short* __restrict__ y_ws, const short* __restrict__ wp_bf,
            const float* __restrict__ pb, float* __restrict__ out) {
  __shared__ short ys[64 * 136];
  __shared__ short wl[128 * 136];
  const int t = threadIdx.x;
  const int m0 = blockIdx.x * 64;
  {
    const int r = t >> 2, c0 = (t & 3) * 32;
    const s16x4* src = (const s16x4*)(y_ws + (size_t)(m0 + r) * DIM + c0);
    short* dst = ys + r * 136 + c0;
    #pragma unroll
    for (int i = 0; i < 8; ++i) *(s16x4*)(dst + 4*i) = src[i];
  }
  {
    const int r = t >> 1, c0 = (t & 1) * 64;
    const short* src = wp_bf + (size_t)r * DIM + c0;
    short* dst = wl + r * 136 + c0;
    #pragma unroll
    for (int i = 0; i < 8; ++i)
      *(s16x8*)(dst + 8*i) = *(const s16x8*)(src + 8*i);
  }
  __syncthreads();
  const int l = t & 63, w = t >> 6, lr = l & 15, g = l >> 4;
  const int m = m0 + w * 16 + lr;
  f32x4 acc[8] = {};
  #pragma unroll
  for (int ks = 0; ks < 4; ++ks) {
    const int k0 = ks * 32 + 4 * g;
    Frag ya;
    const short* bp = ys + (w * 16 + lr) * 136 + k0;
    ya.h.lo = *(const s16x4*)bp; ya.h.hi = *(const s16x4*)(bp + 16);
    #pragma unroll
    for (int ct = 0; ct < 8; ++ct) {
      const short* ap = wl + (ct * 16 + lr) * 136 + k0;
      Frag wa; wa.h.lo = *(const s16x4*)ap; wa.h.hi = *(const s16x4*)(ap + 16);
      acc[ct] = __builtin_amdgcn_mfma_f32_16x16x32_bf16(wa.v, ya.v, acc[ct], 0, 0, 0);
    }
  }
  #pragma unroll
  for (int ct = 0; ct < 8; ++ct) {
    const int c0 = ct * 16 + 4 * g;
    const f32x4 pbv = *(const f32x4*)(pb + c0);
    f32x4 res = acc[ct] + pbv;
    *(f32x4*)(out + (size_t)m * DIM + c0) = res;
  }
}

extern "C" void kernel_launch(void* const* d_in, const int* in_sizes, int n_in,
                              void* d_out, int out_size, void* d_ws, size_t ws_size,
                              hipStream_t stream) {
  const float* x    = (const float*)d_in[0];
  const float* mask = (const float*)d_in[1];
  const float* bt   = (const float*)d_in[2];
  const int*   ri   = (const int*)d_in[3];
  const float* qkvw = (const float*)d_in[4];
  const float* pw   = (const float*)d_in[5];
  const float* pb   = (const float*)d_in[6];
  float* out = (float*)d_out;
  // ws layout: 4 x 25.69MB bf16 tensors + 1.3MB bias_perm + 128KB bf16 weights
  const size_t TEN = (size_t)256 * NH * NTOK * HD;   // 12,845,056
  short* q_ws = (short*)d_ws;
  short* k_ws = q_ws + TEN;
  short* v_ws = k_ws + TEN;
  short* y_ws = v_ws + TEN;
  short* bias_perm = y_ws + TEN;                     // NH*NTOK*BPQ shorts
  short* wq_bf = bias_perm + (size_t)NH * NTOK * BPQ; // 3*128*128 shorts
  short* wp_bf = wq_bf + 3 * DIM * DIM;               // 128*128 shorts
  k_biasperm<<<(NH * NTOK * BPQ + 255) / 256, 256, 0, stream>>>(bt, ri, bias_perm);
  k_wprep<<<(3 * DIM * DIM + 255) / 256, 256, 0, stream>>>(qkvw, pw, wq_bf, wp_bf);
  k_qkv<<<1568, 256, 0, stream>>>(x, wq_bf, q_ws, k_ws, v_ws);
  k_attn<<<1024, 512, 0, stream>>>(q_ws, k_ws, v_ws, mask, bias_perm, y_ws);
  k_proj<<<1568, 256, 0, stream>>>(y_ws, wp_bf, pb, out);
}

// Round 9
// 200.189 us; speedup vs baseline: 2.2156x; 1.0137x over previous
//
#include <hip/hip_runtime.h>
#include <hip/hip_bf16.h>
#include <stdint.h>

#define NTOK 392
#define DIM  128
#define NH   4
#define HD   32
#define NKVP 416   // 13*32 padded keys
#define NCH  13
#define KST  36    // K_lds stride (shorts): measured conflict-free
#define VST  420   // Vt_lds stride (shorts): measured conflict-free
#define L2E  1.44269504f
#define BPQ  416   // bias_perm shorts per q-row (13*32)

typedef __attribute__((ext_vector_type(4))) float f32x4;
typedef __attribute__((ext_vector_type(4))) short s16x4;
typedef __attribute__((ext_vector_type(8))) short s16x8;

union Frag { s16x8 v; struct { s16x4 lo, hi; } h; };
union PF { s16x8 v; uint32_t u[4]; };

__device__ __forceinline__ short f2bf(float f) {
  union { float f; uint32_t u; } v; v.f = f;
  uint32_t r = v.u + 0x7fffu + ((v.u >> 16) & 1u);
  return (short)(r >> 16);
}
__device__ __forceinline__ s16x4 cvt4(f32x4 a) {
  s16x4 r; r.x = f2bf(a.x); r.y = f2bf(a.y); r.z = f2bf(a.z); r.w = f2bf(a.w);
  return r;
}
// raw v_exp_f32 (args bounded: <= ~12 by defer-max; denorm flush OK)
__device__ __forceinline__ float fexp2(float x) {
  float r; asm("v_exp_f32 %0, %1" : "=v"(r) : "v"(x)); return r;
}
// bf16x8 -> 2x f32x4 (2 VALU per dword: shl16 / and-hi)
__device__ __forceinline__ void bb2f(s16x8 b, f32x4& lo, f32x4& hi) {
  union { s16x8 s; uint32_t u[4]; } x; x.s = b;
  union { uint32_t u; float f; } t;
  t.u = x.u[0] << 16;          lo.x = t.f;
  t.u = x.u[0] & 0xffff0000u;  lo.y = t.f;
  t.u = x.u[1] << 16;          lo.z = t.f;
  t.u = x.u[1] & 0xffff0000u;  lo.w = t.f;
  t.u = x.u[2] << 16;          hi.x = t.f;
  t.u = x.u[2] & 0xffff0000u;  hi.y = t.f;
  t.u = x.u[3] << 16;          hi.z = t.f;
  t.u = x.u[3] & 0xffff0000u;  hi.w = t.f;
}

// online-softmax + PV step; s0/s1 already include mask+bias (via MFMA C-init)
__device__ __forceinline__ void sm_pv(f32x4 s0, f32x4 s1,
                                      f32x4& o0, f32x4& o1,
                                      float& mrun, float& nmrl, float& lrun,
                                      const Frag& vf0, const Frag& vf1) {
  float cm = fmaxf(fmaxf(fmaxf(s0.x, s0.y), fmaxf(s0.z, s0.w)),
                   fmaxf(fmaxf(s1.x, s1.y), fmaxf(s1.z, s1.w)));
  if (__any(cm > mrun + 8.f)) {         // rare: true running-max rescale
    float tmx = fmaxf(cm, __shfl_xor(cm, 16));
    tmx = fmaxf(tmx, __shfl_xor(tmx, 32));
    const float mnew = fmaxf(mrun, tmx);
    const float al = fexp2((mrun - mnew) * L2E);
    #pragma unroll
    for (int rr = 0; rr < 4; ++rr) { o0[rr] *= al; o1[rr] *= al; }
    lrun *= al; mrun = mnew; nmrl = -mnew * L2E;
  }
  float p0 = fexp2(fmaf(s0.x, L2E, nmrl));
  float p1 = fexp2(fmaf(s0.y, L2E, nmrl));
  float p2 = fexp2(fmaf(s0.z, L2E, nmrl));
  float p3 = fexp2(fmaf(s0.w, L2E, nmrl));
  float p4 = fexp2(fmaf(s1.x, L2E, nmrl));
  float p5 = fexp2(fmaf(s1.y, L2E, nmrl));
  float p6 = fexp2(fmaf(s1.z, L2E, nmrl));
  float p7 = fexp2(fmaf(s1.w, L2E, nmrl));
  lrun += ((p0 + p1) + (p2 + p3)) + ((p4 + p5) + (p6 + p7));
  PF pf;
  asm("v_cvt_pk_bf16_f32 %0, %1, %2" : "=v"(pf.u[0]) : "v"(p0), "v"(p1));
  asm("v_cvt_pk_bf16_f32 %0, %1, %2" : "=v"(pf.u[1]) : "v"(p2), "v"(p3));
  asm("v_cvt_pk_bf16_f32 %0, %1, %2" : "=v"(pf.u[2]) : "v"(p4), "v"(p5));
  asm("v_cvt_pk_bf16_f32 %0, %1, %2" : "=v"(pf.u[3]) : "v"(p6), "v"(p7));
  o0 = __builtin_amdgcn_mfma_f32_16x16x32_bf16(vf0.v, pf.v, o0, 0, 0, 0);
  o1 = __builtin_amdgcn_mfma_f32_16x16x32_bf16(vf1.v, pf.v, o1, 0, 0, 0);
}

// ---- K0a: bias -> frag-ordered bf16 [h][q][c][g][hb][j], pad kv poisoned ----
__global__ void k_biasperm(const float* __restrict__ bt, const int* __restrict__ ri,
                           short* __restrict__ bias_perm) {
  int i = blockIdx.x * 256 + threadIdx.x;
  if (i >= NH * NTOK * BPQ) return;
  int h = i / (NTOK * BPQ);
  int r = i - h * (NTOK * BPQ);
  int q = r / BPQ;
  int p = r - q * BPQ;               // c*32 + g*8 + hb*4 + j
  int c = p >> 5, w2 = p & 31;
  int g = w2 >> 3, hb = (w2 >> 2) & 1, jj = w2 & 3;
  int kv = c * 32 + hb * 16 + g * 4 + jj;
  float v = -3e30f;
  if (kv < NTOK) v = bt[ri[q * NTOK + kv] * NH + h];
  bias_perm[i] = f2bf(v);
}

// ---- K0b: weights -> bf16 (one-time; kills per-block cvt in K1/K3) ---------
__global__ void k_wprep(const float* __restrict__ qkvw, const float* __restrict__ pw,
                        short* __restrict__ wq_bf, short* __restrict__ wp_bf) {
  int i = blockIdx.x * 256 + threadIdx.x;
  if (i < 3 * DIM * DIM) wq_bf[i] = f2bf(qkvw[i]);
  if (i < DIM * DIM)     wp_bf[i] = f2bf(pw[i]);
}

// ------- K1: qkv = x @ qkv_w^T, bf16 out, q pre-scaled; fused z-loop ---------
__global__ __launch_bounds__(256, 2)
void k_qkv(const float* __restrict__ x, const short* __restrict__ wq_bf,
           short* __restrict__ q_ws, short* __restrict__ k_ws,
           short* __restrict__ v_ws) {
  __shared__ short xs[64 * 136];
  __shared__ short wl[128 * 136];
  const int t  = threadIdx.x;
  const int m0 = blockIdx.x * 64;
  {
    const int r = t >> 2, c0 = (t & 3) * 32;
    const float* src = x + (size_t)(m0 + r) * DIM + c0;
    short* dst = xs + r * 136 + c0;
    #pragma unroll
    for (int i = 0; i < 8; ++i)
      *(s16x4*)(dst + 4*i) = cvt4(*(const f32x4*)(src + 4*i));
  }
  const int l = t & 63, w = t >> 6, lr = l & 15, g = l >> 4;
  const int m = m0 + w * 16 + lr;
  const int b = m / NTOK;
  const int n = m - b * NTOK;
  #pragma unroll 1
  for (int z = 0; z < 3; ++z) {
    {
      const int r = t >> 1, c0 = (t & 1) * 64;
      const short* src = wq_bf + (size_t)(z * DIM + r) * DIM + c0;
      short* dst = wl + r * 136 + c0;
      #pragma unroll
      for (int i = 0; i < 8; ++i)
        *(s16x8*)(dst + 8*i) = *(const s16x8*)(src + 8*i);
    }
    __syncthreads();
    f32x4 acc[8] = {};
    #pragma unroll
    for (int ks = 0; ks < 4; ++ks) {
      const int k0 = ks * 32 + 4 * g;
      Frag xb;
      const short* bp = xs + (w * 16 + lr) * 136 + k0;
      xb.h.lo = *(const s16x4*)bp; xb.h.hi = *(const s16x4*)(bp + 16);
      #pragma unroll
      for (int ct = 0; ct < 8; ++ct) {
        const short* ap = wl + (ct * 16 + lr) * 136 + k0;
        Frag wa; wa.h.lo = *(const s16x4*)ap; wa.h.hi = *(const s16x4*)(ap + 16);
        acc[ct] = __builtin_amdgcn_mfma_f32_16x16x32_bf16(wa.v, xb.v, acc[ct], 0, 0, 0);
      }
    }
    short* outp = (z == 0) ? q_ws : (z == 1 ? k_ws : v_ws);
    const float scale = (z == 0) ? 0.17677669529663689f : 1.0f;
    #pragma unroll
    for (int ct = 0; ct < 8; ++ct) {
      const int c0 = ct * 16 + 4 * g;       // 4 consecutive channels
      const int hh = c0 >> 5, d = c0 & 31;
      f32x4 sc = acc[ct];
      sc.x *= scale; sc.y *= scale; sc.z *= scale; sc.w *= scale;
      *(s16x4*)(outp + (((size_t)b * NH + hh) * NTOK + n) * HD + d) = cvt4(sc);
    }
    __syncthreads();
  }
}

// ---- K2: per-(window,head) attention, single stream, unrolled chunks, ------
// ---- distance-2 raw prefetch; mask+bias folded into MFMA accumulator; ------
// ---- raw v_exp_f32 ---------------------------------------------------------
__global__ __launch_bounds__(512, 4)
void k_attn(const short* __restrict__ q_ws, const short* __restrict__ k_ws,
            const short* __restrict__ v_ws, const float* __restrict__ mask,
            const short* __restrict__ bias_perm, short* __restrict__ y_ws) {
  __shared__ short K_l[NKVP * KST];   // [kv][d]
  __shared__ short Vt[HD * VST];      // [d][kv]
  const int t = threadIdx.x;
  // XCD swizzle: 4 heads of one window land on the same XCD, adjacent slots
  const int j = blockIdx.x, xcd = j & 7, slot = j >> 3;
  const int b = (xcd << 5) | (slot >> 2);
  const int h = slot & 3;
  const size_t bh = (size_t)b * NH + h;
  const short* kp = k_ws + bh * NTOK * HD;
  const short* vp = v_ws + bh * NTOK * HD;
  const short* qp = q_ws + bh * NTOK * HD;
  const float* mp = mask + (size_t)b * NTOK * NTOK;
  const short* bph = bias_perm + (size_t)h * NTOK * BPQ;
  // stage K (+ zero pad rows)
  for (int r = t; r < NKVP; r += 512) {
    short* dst = K_l + r * KST;
    if (r < NTOK) {
      const s16x4* src = (const s16x4*)(kp + r * HD);
      #pragma unroll
      for (int i = 0; i < 8; ++i) *(s16x4*)(dst + 4*i) = src[i];
    } else {
      s16x4 zz = {0, 0, 0, 0};
      #pragma unroll
      for (int i = 0; i < 8; ++i) *(s16x4*)(dst + 4*i) = zz;
    }
  }
  // stage V transposed
  for (int n = t; n < NTOK; n += 512) {
    union { s16x4 v4[8]; short s[32]; } vv;
    const s16x4* src = (const s16x4*)(vp + n * HD);
    #pragma unroll
    for (int i = 0; i < 8; ++i) vv.v4[i] = src[i];
    #pragma unroll
    for (int d = 0; d < 32; ++d) Vt[d * VST + n] = vv.s[d];
  }
  // zero pad Vt cols [NTOK, VST)
  for (int i = t; i < HD * (VST - NTOK); i += 512) {
    int d = i / (VST - NTOK), c = NTOK + i % (VST - NTOK);
    Vt[d * VST + c] = 0;
  }
  __syncthreads();
  const int l = t & 63, w = t >> 6, lr = l & 15, g = l >> 4;
  const int og0 = 4 * g, og1 = 16 + 4 * g;
  #pragma unroll 1
  for (int q0 = w * 16; q0 < NTOK; q0 += 128) {
    const int qrow = q0 + lr;
    const int qc = qrow < NTOK ? qrow : NTOK - 1;
    Frag qf;
    { const short* qa = qp + qc * HD + 4 * g;
      qf.h.lo = *(const s16x4*)qa; qf.h.hi = *(const s16x4*)(qa + 16); }
    const float* mrow = mp + (size_t)qc * NTOK;
    const short* brow = bph + qc * BPQ;
    f32x4 mm0[3], mm1[3];   // raw mask slots (no arithmetic at issue!)
    s16x8 bb[3];            // raw bias slots (bf16, poison baked in)
    #pragma unroll
    for (int c = 0; c < 2; ++c) {
      mm0[c] = *(const f32x4*)(mrow + c * 32 + og0);
      mm1[c] = *(const f32x4*)(mrow + c * 32 + og1);
      bb[c]  = *(const s16x8*)(brow + c * 32 + g * 8);
    }
    f32x4 o0 = {0,0,0,0}, o1 = {0,0,0,0};
    float mrun = 0.f, nmrl = 0.f, lrun = 0.f;
    #pragma unroll
    for (int c = 0; c < NCH; ++c) {
      const int sl = c % 3;             // static after unroll
      if (c + 2 < NCH) {
        const int cc = c + 2, s2 = (c + 2) % 3;
        int a0 = cc * 32 + og0, a1 = cc * 32 + og1;
        if (cc == NCH - 1) { a0 = a0 > 388 ? 388 : a0; a1 = 388; }  // no OOB; poisoned via bias
        mm0[s2] = *(const f32x4*)(mrow + a0);
        mm1[s2] = *(const f32x4*)(mrow + a1);
        bb[s2]  = *(const s16x8*)(brow + cc * 32 + g * 8);
      }
      const int kv0 = c * 32;
      Frag ka0, ka1, vf0, vf1;
      { const short* p0 = K_l + (kv0 + lr) * KST + 4 * g;
        ka0.h.lo = *(const s16x4*)p0; ka0.h.hi = *(const s16x4*)(p0 + 16);
        const short* p1 = K_l + (kv0 + 16 + lr) * KST + 4 * g;
        ka1.h.lo = *(const s16x4*)p1; ka1.h.hi = *(const s16x4*)(p1 + 16);
        const short* v0 = Vt + lr * VST + kv0 + 4 * g;
        vf0.h.lo = *(const s16x4*)v0; vf0.h.hi = *(const s16x4*)(v0 + 16);
        const short* v1 = Vt + (16 + lr) * VST + kv0 + 4 * g;
        vf1.h.lo = *(const s16x4*)v1; vf1.h.hi = *(const s16x4*)(v1 + 16); }
      // C-init = mask + bias (computed from 2-chunk-old regs, off critical path)
      f32x4 blo, bhi;
      bb2f(bb[sl], blo, bhi);
      f32x4 c0 = mm0[sl] + blo;
      f32x4 c1 = mm1[sl] + bhi;
      f32x4 s0 = __builtin_amdgcn_mfma_f32_16x16x32_bf16(ka0.v, qf.v, c0, 0,0,0);
      f32x4 s1 = __builtin_amdgcn_mfma_f32_16x16x32_bf16(ka1.v, qf.v, c1, 0,0,0);
      sm_pv(s0, s1, o0, o1, mrun, nmrl, lrun, vf0, vf1);
    }
    float lt = lrun + __shfl_xor(lrun, 16);
    lt += __shfl_xor(lt, 32);
    if (qrow < NTOK) {
      const float inv = 1.0f / lt;
      short* yb = y_ws + ((size_t)b * NTOK + qrow) * DIM + h * HD;
      s16x4 r0, r1;
      #pragma unroll
      for (int rr = 0; rr < 4; ++rr) { r0[rr] = f2bf(o0[rr] * inv); r1[rr] = f2bf(o1[rr] * inv); }
      *(s16x4*)(yb + 4 * g) = r0;
      *(s16x4*)(yb + 16 + 4 * g) = r1;
    }
  }
}

// ---------------- K3: out = y @ proj_w^T + proj_b -----------------------------
__global__ __launch_bounds__(256, 2)
void k_proj(const short* __restrict__ y_ws, const short* __restrict__ wp_bf,
            const float* __restrict__ pb, float* __restrict__ out) {
  __shared__ short ys[64 * 136];
  __shared__ short wl[128 * 136];
  const int t = threadIdx.x;
  const int m0 = blockIdx.x * 64;
  {
    const int r = t >> 2, c0 = (t & 3) * 32;
    const s16x4* src = (const s16x4*)(y_ws + (size_t)(m0 + r) * DIM + c0);
    short* dst = ys + r * 136 + c0;
    #pragma unroll
    for (int i = 0; i < 8; ++i) *(s16x4*)(dst + 4*i) = src[i];
  }
  {
    const int r = t >> 1, c0 = (t & 1) * 64;
    const short* src = wp_bf + (size_t)r * DIM + c0;
    short* dst = wl + r * 136 + c0;
    #pragma unroll
    for (int i = 0; i < 8; ++i)
      *(s16x8*)(dst + 8*i) = *(const s16x8*)(src + 8*i);
  }
  __syncthreads();
  const int l = t & 63, w = t >> 6, lr = l & 15, g = l >> 4;
  const int m = m0 + w * 16 + lr;
  f32x4 acc[8] = {};
  #pragma unroll
  for (int ks = 0; ks < 4; ++ks) {
    const int k0 = ks * 32 + 4 * g;
    Frag ya;
    const short* bp = ys + (w * 16 + lr) * 136 + k0;
    ya.h.lo = *(const s16x4*)bp; ya.h.hi = *(const s16x4*)(bp + 16);
    #pragma unroll
    for (int ct = 0; ct < 8; ++ct) {
      const short* ap = wl + (ct * 16 + lr) * 136 + k0;
      Frag wa; wa.h.lo = *(const s16x4*)ap; wa.h.hi = *(const s16x4*)(ap + 16);
      acc[ct] = __builtin_amdgcn_mfma_f32_16x16x32_bf16(wa.v, ya.v, acc[ct], 0, 0, 0);
    }
  }
  #pragma unroll
  for (int ct = 0; ct < 8; ++ct) {
    const int c0 = ct * 16 + 4 * g;
    const f32x4 pbv = *(const f32x4*)(pb + c0);
    f32x4 res = acc[ct] + pbv;
    *(f32x4*)(out + (size_t)m * DIM + c0) = res;
  }
}

extern "C" void kernel_launch(void* const* d_in, const int* in_sizes, int n_in,
                              void* d_out, int out_size, void* d_ws, size_t ws_size,
                              hipStream_t stream) {
  const float* x    = (const float*)d_in[0];
  const float* mask = (const float*)d_in[1];
  const float* bt   = (const float*)d_in[2];
  const int*   ri   = (const int*)d_in[3];
  const float* qkvw = (const float*)d_in[4];
  const float* pw   = (const float*)d_in[5];
  const float* pb   = (const float*)d_in[6];
  float* out = (float*)d_out;
  // ws layout: 4 x 25.69MB bf16 tensors + 1.3MB bias_perm + 128KB bf16 weights
  const size_t TEN = (size_t)256 * NH * NTOK * HD;   // 12,845,056
  short* q_ws = (short*)d_ws;
  short* k_ws = q_ws + TEN;
  short* v_ws = k_ws + TEN;
  short* y_ws = v_ws + TEN;
  short* bias_perm = y_ws + TEN;                     // NH*NTOK*BPQ shorts
  short* wq_bf = bias_perm + (size_t)NH * NTOK * BPQ; // 3*128*128 shorts
  short* wp_bf = wq_bf + 3 * DIM * DIM;               // 128*128 shorts
  k_biasperm<<<(NH * NTOK * BPQ + 255) / 256, 256, 0, stream>>>(bt, ri, bias_perm);
  k_wprep<<<(3 * DIM * DIM + 255) / 256, 256, 0, stream>>>(qkvw, pw, wq_bf, wp_bf);
  k_qkv<<<1568, 256, 0, stream>>>(x, wq_bf, q_ws, k_ws, v_ws);
  k_attn<<<1024, 512, 0, stream>>>(q_ws, k_ws, v_ws, mask, bias_perm, y_ws);
  k_proj<<<1568, 256, 0, stream>>>(y_ws, wp_bf, pb, out);
}